// Round 10
// baseline (128.140 us; speedup 1.0000x reference)
//
#include <hip/hip_runtime.h>
#include <math.h>

#define C2 2.8853900817779268f   // 2*log2(e)

// prep: EkT[b][t8][hh2][g16][k32][hi4] = exp2(C2 * K[b][k=t*32+k32][h=hh*64+g*4+hi])
__global__ __launch_bounds__(512) void addattn_prep(const float* __restrict__ k_g,
                                                    float* __restrict__ ekt)
{
    int tid = blockIdx.x * 512 + threadIdx.x;   // 262144 threads
    int b   = tid >> 13;
    int r   = tid & 8191;
    int h4  = r >> 8;           // 0..31 (h-group of 4)
    int k   = r & 255;          // 0..255
    float4 kv = *(const float4*)(k_g + ((size_t)(b * 256 + k)) * 128 + (h4 << 2));
    float4 E;
    E.x = __builtin_amdgcn_exp2f(C2 * kv.x);
    E.y = __builtin_amdgcn_exp2f(C2 * kv.y);
    E.z = __builtin_amdgcn_exp2f(C2 * kv.z);
    E.w = __builtin_amdgcn_exp2f(C2 * kv.w);
    *(float4*)(ekt + (size_t)b * 32768 + ((k >> 5) << 12) + ((h4 >> 4) << 11)
               + ((h4 & 15) << 7) + ((k & 31) << 2)) = E;
}

// main: 512 blocks x 256 thr (4 waves). Wave = 4 q rows. ZERO barriers.
// Ek and V read straight from global (L2-hot); LDS only for wave-private
// Eq / w / scores (same-wave ds ordering, no __syncthreads anywhere).
__global__ __launch_bounds__(256) void addattn_kernel(
    const float* __restrict__ q_g, const float* __restrict__ ekt,
    const float* __restrict__ v_g, const float* __restrict__ w_g,
    float* __restrict__ out)
{
    __shared__ float sattn[4096];   // 16 KB: per-wave [4 rows][256] scores -> attn
    __shared__ float eqst[2048];    //  8 KB: per-wave [4 rows][128] Eq
    __shared__ float wlds[512];     //  2 KB: per-wave w[128] copy

    const int tid  = threadIdx.x;   // 0..255
    const int lane = tid & 63;
    const int wv   = tid >> 6;      // 0..3
    const int kk   = lane & 31;     // k within tile (score) / h-chunk (PV)
    const int hh   = lane >> 5;     // h-half (score) / k-half (PV)

    // XCD-grouped remap: 4 whole batches per XCD -> ekt/V/Q stay L2-hot
    const int o   = ((blockIdx.x & 7) << 6) + (blockIdx.x >> 3);
    const int b   = o >> 4;
    const int q0  = (o & 15) << 4;
    const int qr0 = q0 + (wv << 2);   // wave's first q row

    // per-wave w copy (wave-private -> no barrier)
    if (lane < 32) ((float4*)&wlds[wv << 7])[lane] = ((const float4*)w_g)[lane];

    // Eq = exp2(C2*q) for the wave's 4 rows (wave-private)
    {
        const float* qb = q_g + (size_t)(b * 256 + qr0) * 128;
        #pragma unroll
        for (int j = 0; j < 2; ++j) {
            int f = lane + (j << 6);       // float4 index into [4 rows][32]
            int r = f >> 5, c = f & 31;
            float4 qv = *(const float4*)(qb + (r << 7) + (c << 2));
            float4 E;
            E.x = __builtin_amdgcn_exp2f(C2 * qv.x);
            E.y = __builtin_amdgcn_exp2f(C2 * qv.y);
            E.z = __builtin_amdgcn_exp2f(C2 * qv.z);
            E.w = __builtin_amdgcn_exp2f(C2 * qv.w);
            *(float4*)&eqst[(wv << 9) + (r << 7) + (c << 2)] = E;
        }
    }

    const float4* ek4 = (const float4*)(ekt + (size_t)b * 32768);
    const float4* vg4 = (const float4*)(v_g + (size_t)b * 32768);
    const float* eqp = eqst + (wv << 9) + (hh << 6);   // + r*128 + g*4
    const float* wb  = wlds + (wv << 7) + (hh << 6);   // + g*4
    float* srow = sattn + (wv << 10);                  // [r*256 + k]

    // ---- score phase: 8 tiles of 32 k; Ek from global; 4-way rational batching ----
    #pragma unroll 1
    for (int t = 0; t < 8; ++t) {
        const float4* kb = ek4 + (t << 10) + (hh << 9) + kk;
        float s0 = 0.f, s1 = 0.f, s2 = 0.f, s3 = 0.f;
        #pragma unroll
        for (int g = 0; g < 16; ++g) {
            float4 k4 = kb[g << 5];                               // global, L2-hot
            float4 w4 = *(const float4*)(wb + (g << 2));          // LDS bcast
            float4 e0 = *(const float4*)(eqp + (g << 2));
            float4 e1 = *(const float4*)(eqp + 128 + (g << 2));
            float4 e2 = *(const float4*)(eqp + 256 + (g << 2));
            float4 e3 = *(const float4*)(eqp + 384 + (g << 2));
            // per row: sum_{i<4} w_i/d_i = num/(d0 d1 d2 d3), one rcp per 4 elems
            {
                float d0 = fmaf(e0.x, k4.x, 1.f), d1 = fmaf(e0.y, k4.y, 1.f);
                float d2 = fmaf(e0.z, k4.z, 1.f), d3 = fmaf(e0.w, k4.w, 1.f);
                float P01 = d0 * d1, P23 = d2 * d3;
                float N01 = fmaf(w4.x, d1, w4.y * d0);
                float N23 = fmaf(w4.z, d3, w4.w * d2);
                float num = fmaf(N01, P23, N23 * P01);
                s0 = fmaf(num, __builtin_amdgcn_rcpf(P01 * P23), s0);
            }
            {
                float d0 = fmaf(e1.x, k4.x, 1.f), d1 = fmaf(e1.y, k4.y, 1.f);
                float d2 = fmaf(e1.z, k4.z, 1.f), d3 = fmaf(e1.w, k4.w, 1.f);
                float P01 = d0 * d1, P23 = d2 * d3;
                float N01 = fmaf(w4.x, d1, w4.y * d0);
                float N23 = fmaf(w4.z, d3, w4.w * d2);
                float num = fmaf(N01, P23, N23 * P01);
                s1 = fmaf(num, __builtin_amdgcn_rcpf(P01 * P23), s1);
            }
            {
                float d0 = fmaf(e2.x, k4.x, 1.f), d1 = fmaf(e2.y, k4.y, 1.f);
                float d2 = fmaf(e2.z, k4.z, 1.f), d3 = fmaf(e2.w, k4.w, 1.f);
                float P01 = d0 * d1, P23 = d2 * d3;
                float N01 = fmaf(w4.x, d1, w4.y * d0);
                float N23 = fmaf(w4.z, d3, w4.w * d2);
                float num = fmaf(N01, P23, N23 * P01);
                s2 = fmaf(num, __builtin_amdgcn_rcpf(P01 * P23), s2);
            }
            {
                float d0 = fmaf(e3.x, k4.x, 1.f), d1 = fmaf(e3.y, k4.y, 1.f);
                float d2 = fmaf(e3.z, k4.z, 1.f), d3 = fmaf(e3.w, k4.w, 1.f);
                float P01 = d0 * d1, P23 = d2 * d3;
                float N01 = fmaf(w4.x, d1, w4.y * d0);
                float N23 = fmaf(w4.z, d3, w4.w * d2);
                float num = fmaf(N01, P23, N23 * P01);
                s3 = fmaf(num, __builtin_amdgcn_rcpf(P01 * P23), s3);
            }
        }
        s0 += __shfl_xor(s0, 32);      // combine h-halves
        s1 += __shfl_xor(s1, 32);
        s2 += __shfl_xor(s2, 32);
        s3 += __shfl_xor(s3, 32);
        if (hh == 0) {
            srow[(t << 5) + kk]       = -C2 * s0;
            srow[256 + (t << 5) + kk] = -C2 * s1;
            srow[512 + (t << 5) + kk] = -C2 * s2;
            srow[768 + (t << 5) + kk] = -C2 * s3;
        }
    }

    // ---- softmax: 4 rows, 64-lane each (same-wave LDS ordering, no barrier) ----
    #pragma unroll
    for (int r = 0; r < 4; ++r) {
        float4 sv = *(const float4*)&srow[(r << 8) + (lane << 2)];
        float mx = fmaxf(fmaxf(sv.x, sv.y), fmaxf(sv.z, sv.w));
        #pragma unroll
        for (int off = 32; off; off >>= 1) mx = fmaxf(mx, __shfl_xor(mx, off));
        float ex = __builtin_amdgcn_exp2f(sv.x - mx);
        float ey = __builtin_amdgcn_exp2f(sv.y - mx);
        float ez = __builtin_amdgcn_exp2f(sv.z - mx);
        float ew = __builtin_amdgcn_exp2f(sv.w - mx);
        float sum = (ex + ey) + (ez + ew);
        #pragma unroll
        for (int off = 32; off; off >>= 1) sum += __shfl_xor(sum, off);
        float inv = __builtin_amdgcn_rcpf(sum);
        float4 at; at.x = ex * inv; at.y = ey * inv; at.z = ez * inv; at.w = ew * inv;
        *(float4*)&srow[(r << 8) + (lane << 2)] = at;
    }

    // ---- PV: V straight from global; lane = h-chunk kk, k-half hh; 4 rows ----
    float4 a0, a1, a2, a3;
    a0.x = a0.y = a0.z = a0.w = 0.f;
    a1.x = a1.y = a1.z = a1.w = 0.f;
    a2.x = a2.y = a2.z = a2.w = 0.f;
    a3.x = a3.y = a3.z = a3.w = 0.f;
    #pragma unroll 1
    for (int t = 0; t < 8; ++t) {
        const float4* vb = vg4 + (t << 10) + (hh << 9) + kk;   // k = t*32+hh*16+..., h-chunk kk
        const float* ab  = srow + (t << 5) + (hh << 4);
        #pragma unroll
        for (int g = 0; g < 4; ++g) {
            float4 t0 = *(const float4*)(ab + (g << 2));          // attn bcast (LDS)
            float4 t1 = *(const float4*)(ab + 256 + (g << 2));
            float4 t2 = *(const float4*)(ab + 512 + (g << 2));
            float4 t3 = *(const float4*)(ab + 768 + (g << 2));
            #pragma unroll
            for (int i = 0; i < 4; ++i) {
                float4 vv = vb[((g << 2) + i) << 5];              // global, L2-hot
                float c0 = (&t0.x)[i], c1 = (&t1.x)[i], c2 = (&t2.x)[i], c3 = (&t3.x)[i];
                a0.x = fmaf(c0, vv.x, a0.x); a0.y = fmaf(c0, vv.y, a0.y);
                a0.z = fmaf(c0, vv.z, a0.z); a0.w = fmaf(c0, vv.w, a0.w);
                a1.x = fmaf(c1, vv.x, a1.x); a1.y = fmaf(c1, vv.y, a1.y);
                a1.z = fmaf(c1, vv.z, a1.z); a1.w = fmaf(c1, vv.w, a1.w);
                a2.x = fmaf(c2, vv.x, a2.x); a2.y = fmaf(c2, vv.y, a2.y);
                a2.z = fmaf(c2, vv.z, a2.z); a2.w = fmaf(c2, vv.w, a2.w);
                a3.x = fmaf(c3, vv.x, a3.x); a3.y = fmaf(c3, vv.y, a3.y);
                a3.z = fmaf(c3, vv.z, a3.z); a3.w = fmaf(c3, vv.w, a3.w);
            }
        }
    }

    // combine k-halves
    a0.x += __shfl_xor(a0.x, 32); a0.y += __shfl_xor(a0.y, 32);
    a0.z += __shfl_xor(a0.z, 32); a0.w += __shfl_xor(a0.w, 32);
    a1.x += __shfl_xor(a1.x, 32); a1.y += __shfl_xor(a1.y, 32);
    a1.z += __shfl_xor(a1.z, 32); a1.w += __shfl_xor(a1.w, 32);
    a2.x += __shfl_xor(a2.x, 32); a2.y += __shfl_xor(a2.y, 32);
    a2.z += __shfl_xor(a2.z, 32); a2.w += __shfl_xor(a2.w, 32);
    a3.x += __shfl_xor(a3.x, 32); a3.y += __shfl_xor(a3.y, 32);
    a3.z += __shfl_xor(a3.z, 32); a3.w += __shfl_xor(a3.w, 32);

    if (hh == 0) {
        float* ob = out + (size_t)(b * 256 + qr0) * 128 + (kk << 2);
        *(float4*)(ob)       = a0;
        *(float4*)(ob + 128) = a1;
        *(float4*)(ob + 256) = a2;
        *(float4*)(ob + 384) = a3;
    }
}

extern "C" void kernel_launch(void* const* d_in, const int* in_sizes, int n_in,
                              void* d_out, int out_size, void* d_ws, size_t ws_size,
                              hipStream_t stream) {
    const float* q = (const float*)d_in[0];
    const float* k = (const float*)d_in[1];
    const float* v = (const float*)d_in[2];
    const float* w = (const float*)d_in[3];
    float* out = (float*)d_out;
    float* ekt = (float*)d_ws;                 // 32*256*128*4 = 4 MB scratch
    addattn_prep<<<512, 512, 0, stream>>>(k, ekt);
    addattn_kernel<<<512, 256, 0, stream>>>(q, ekt, v, w, out);
}

// Round 11
// 73.652 us; speedup vs baseline: 1.7398x; 1.7398x over previous
//
#include <hip/hip_runtime.h>
#include <math.h>

#define C2 2.8853900817779268f   // 2*log2(e)

__device__ __forceinline__ float rl(float v, int l) {
    return __uint_as_float(__builtin_amdgcn_readlane(__float_as_uint(v), l));
}

// prep: EkT[b][t4][g32][k64][hi4] = exp2(C2 * K[b][k=t*64+k64][h=g*4+hi])
__global__ __launch_bounds__(512) void addattn_prep(const float* __restrict__ k_g,
                                                    float* __restrict__ ekt)
{
    int tid = blockIdx.x * 512 + threadIdx.x;   // 262144
    int b   = tid >> 13;
    int r   = tid & 8191;
    int g   = r >> 8;           // h-chunk of 4 (0..31)
    int k   = r & 255;
    float4 kv = *(const float4*)(k_g + ((size_t)(b * 256 + k)) * 128 + (g << 2));
    float4 E;
    E.x = __builtin_amdgcn_exp2f(C2 * kv.x);
    E.y = __builtin_amdgcn_exp2f(C2 * kv.y);
    E.z = __builtin_amdgcn_exp2f(C2 * kv.z);
    E.w = __builtin_amdgcn_exp2f(C2 * kv.w);
    *(float4*)(ekt + (size_t)(((b << 2) + (k >> 6)) << 5 | g) * 256 + ((k & 63) << 2)) = E;
}

// main: 512 blocks x 256 thr (4 waves). Wave = 4 q rows. NO LDS, NO barriers.
// Score: lane = k (64-k tiles); Eq/w register-resident, broadcast via readlane.
// PV: lane = h-pair; attn broadcast via readlane from score registers.
__global__ __launch_bounds__(256, 5) void addattn_kernel(
    const float* __restrict__ q_g, const float* __restrict__ ekt,
    const float* __restrict__ v_g, const float* __restrict__ w_g,
    float* __restrict__ out)
{
    const int tid  = threadIdx.x;   // 0..255
    const int lane = tid & 63;
    const int wv   = tid >> 6;      // 0..3

    // XCD-grouped remap: 4 whole batches per XCD -> ekt/V/Q stay L2-hot
    const int o   = ((blockIdx.x & 7) << 6) + (blockIdx.x >> 3);
    const int b   = o >> 4;
    const int q0  = (o & 15) << 4;
    const int qr0 = q0 + (wv << 2);   // wave's first q row

    // register-resident w and Eq: lane l holds h = 2l, 2l+1
    float2 w2 = *(const float2*)(w_g + (lane << 1));
    float2 eqA, eqB, eqC, eqD;
    {
        const float* qb = q_g + (size_t)(b * 256 + qr0) * 128 + (lane << 1);
        float2 v0 = *(const float2*)(qb);
        float2 v1 = *(const float2*)(qb + 128);
        float2 v2 = *(const float2*)(qb + 256);
        float2 v3 = *(const float2*)(qb + 384);
        eqA.x = __builtin_amdgcn_exp2f(C2 * v0.x); eqA.y = __builtin_amdgcn_exp2f(C2 * v0.y);
        eqB.x = __builtin_amdgcn_exp2f(C2 * v1.x); eqB.y = __builtin_amdgcn_exp2f(C2 * v1.y);
        eqC.x = __builtin_amdgcn_exp2f(C2 * v2.x); eqC.y = __builtin_amdgcn_exp2f(C2 * v2.y);
        eqD.x = __builtin_amdgcn_exp2f(C2 * v3.x); eqD.y = __builtin_amdgcn_exp2f(C2 * v3.y);
    }

    const float4* ekp = (const float4*)(ekt + (size_t)(b << 2) * 8192);  // [t][g][k64][4]
    float sc[4][4];   // [tile][row] -- statically indexed everywhere

    #pragma unroll
    for (int t = 0; t < 4; ++t) {
        float s0 = 0.f, s1 = 0.f, s2 = 0.f, s3 = 0.f;
        #pragma unroll 4
        for (int g = 0; g < 32; ++g) {
            float4 k4 = ekp[((t << 5) + g << 6) + lane];        // 1KB coalesced, L2-hot
            const int l0 = g << 1, l1 = (g << 1) + 1;
            float wa = rl(w2.x, l0), wb = rl(w2.y, l0);
            float wc = rl(w2.x, l1), wd = rl(w2.y, l1);
            #define ROWBLK(EQ, S)                                             \
            {                                                                 \
                float ea = rl(EQ.x, l0), eb = rl(EQ.y, l0);                   \
                float ec = rl(EQ.x, l1), ed = rl(EQ.y, l1);                   \
                float d0 = fmaf(ea, k4.x, 1.f), d1 = fmaf(eb, k4.y, 1.f);     \
                float d2 = fmaf(ec, k4.z, 1.f), d3 = fmaf(ed, k4.w, 1.f);     \
                float P01 = d0 * d1, P23 = d2 * d3;                           \
                float N01 = fmaf(wa, d1, wb * d0);                            \
                float N23 = fmaf(wc, d3, wd * d2);                            \
                float num = fmaf(N01, P23, N23 * P01);                        \
                S = fmaf(num, __builtin_amdgcn_rcpf(P01 * P23), S);           \
            }
            ROWBLK(eqA, s0)
            ROWBLK(eqB, s1)
            ROWBLK(eqC, s2)
            ROWBLK(eqD, s3)
            #undef ROWBLK
        }
        sc[t][0] = s0; sc[t][1] = s1; sc[t][2] = s2; sc[t][3] = s3;
    }

    // ---- softmax per row, fully in registers (lane holds k = 64t+lane) ----
    float at[4][4];   // attn [tile][row]
    #pragma unroll
    for (int r = 0; r < 4; ++r) {
        float x0 = -C2 * sc[0][r], x1 = -C2 * sc[1][r];
        float x2 = -C2 * sc[2][r], x3 = -C2 * sc[3][r];
        float m = fmaxf(fmaxf(x0, x1), fmaxf(x2, x3));
        #pragma unroll
        for (int off = 32; off; off >>= 1) m = fmaxf(m, __shfl_xor(m, off));
        float e0 = __builtin_amdgcn_exp2f(x0 - m);
        float e1 = __builtin_amdgcn_exp2f(x1 - m);
        float e2 = __builtin_amdgcn_exp2f(x2 - m);
        float e3 = __builtin_amdgcn_exp2f(x3 - m);
        float sum = (e0 + e1) + (e2 + e3);
        #pragma unroll
        for (int off = 32; off; off >>= 1) sum += __shfl_xor(sum, off);
        float inv = __builtin_amdgcn_rcpf(sum);
        at[0][r] = e0 * inv; at[1][r] = e1 * inv;
        at[2][r] = e2 * inv; at[3][r] = e3 * inv;
    }

    // ---- PV: lane owns h = 2*lane, 2*lane+1; attn via readlane ----
    float2 o0, o1, o2, o3;
    o0.x = o0.y = o1.x = o1.y = 0.f;
    o2.x = o2.y = o3.x = o3.y = 0.f;
    const float2* vp = (const float2*)(v_g + (size_t)b * 32768) + lane;   // + k*64
    #pragma unroll
    for (int t = 0; t < 4; ++t) {
        #pragma unroll 8
        for (int j = 0; j < 64; ++j) {
            float2 v2 = vp[((t << 6) + j) << 6];            // 512B coalesced, L1/L2-hot
            float a0 = rl(at[t][0], j);
            float a1 = rl(at[t][1], j);
            float a2 = rl(at[t][2], j);
            float a3 = rl(at[t][3], j);
            o0.x = fmaf(a0, v2.x, o0.x); o0.y = fmaf(a0, v2.y, o0.y);
            o1.x = fmaf(a1, v2.x, o1.x); o1.y = fmaf(a1, v2.y, o1.y);
            o2.x = fmaf(a2, v2.x, o2.x); o2.y = fmaf(a2, v2.y, o2.y);
            o3.x = fmaf(a3, v2.x, o3.x); o3.y = fmaf(a3, v2.y, o3.y);
        }
    }

    float* ob = out + (size_t)(b * 256 + qr0) * 128 + (lane << 1);
    *(float2*)(ob)       = o0;
    *(float2*)(ob + 128) = o1;
    *(float2*)(ob + 256) = o2;
    *(float2*)(ob + 384) = o3;
}

extern "C" void kernel_launch(void* const* d_in, const int* in_sizes, int n_in,
                              void* d_out, int out_size, void* d_ws, size_t ws_size,
                              hipStream_t stream) {
    const float* q = (const float*)d_in[0];
    const float* k = (const float*)d_in[1];
    const float* v = (const float*)d_in[2];
    const float* w = (const float*)d_in[3];
    float* out = (float*)d_out;
    float* ekt = (float*)d_ws;                 // 32*256*128*4 = 4 MB scratch
    addattn_prep<<<512, 512, 0, stream>>>(k, ekt);
    addattn_kernel<<<512, 256, 0, stream>>>(q, ekt, v, w, out);
}

// Round 12
// 60.723 us; speedup vs baseline: 2.1102x; 1.2129x over previous
//
#include <hip/hip_runtime.h>
#include <math.h>

#define C2 2.8853900817779268f   // 2*log2(e)

// prep (1024 blocks x 512):
//  blocks 0..511 : ekt[b][t4][g32][k64][hi4] = exp2(C2 * K[b][k=t*64+k64][h=4g+hi])
//  blocks 512..  : eqs[b][q][h]              = exp2(C2 * Q[b][q][h])
__global__ __launch_bounds__(512) void addattn_prep(const float* __restrict__ k_g,
                                                    const float* __restrict__ q_g,
                                                    float* __restrict__ ekt,
                                                    float* __restrict__ eqs)
{
    if (blockIdx.x < 512) {
        int tid = blockIdx.x * 512 + threadIdx.x;   // 262144
        int b   = tid >> 13;
        int r   = tid & 8191;
        int g   = r >> 8;           // h-chunk of 4 (0..31)
        int k   = r & 255;
        float4 kv = *(const float4*)(k_g + ((size_t)(b * 256 + k)) * 128 + (g << 2));
        float4 E;
        E.x = __builtin_amdgcn_exp2f(C2 * kv.x);
        E.y = __builtin_amdgcn_exp2f(C2 * kv.y);
        E.z = __builtin_amdgcn_exp2f(C2 * kv.z);
        E.w = __builtin_amdgcn_exp2f(C2 * kv.w);
        *(float4*)(ekt + ((size_t)(((b << 2) + (k >> 6)) << 5 | g)) * 256 + ((k & 63) << 2)) = E;
    } else {
        int tid = (blockIdx.x - 512) * 512 + threadIdx.x;   // 262144 float4s
        float4 qv = ((const float4*)q_g)[tid];
        float4 E;
        E.x = __builtin_amdgcn_exp2f(C2 * qv.x);
        E.y = __builtin_amdgcn_exp2f(C2 * qv.y);
        E.z = __builtin_amdgcn_exp2f(C2 * qv.z);
        E.w = __builtin_amdgcn_exp2f(C2 * qv.w);
        ((float4*)eqs)[tid] = E;
    }
}

// main: 512 blocks x 512 thr (8 waves), wave = 2 q rows. No barriers.
// Score: lane=k; Ek from global (coalesced float4); Eq/w via wave-uniform
// scalar loads (SGPR operands). PV: attn via wave-private LDS broadcast.
__global__ __launch_bounds__(512, 4) void addattn_kernel(
    const float* __restrict__ eqs, const float* __restrict__ ekt,
    const float* __restrict__ v_g, const float* __restrict__ w_g,
    float* __restrict__ out)
{
    __shared__ float sattn[4096];   // 16 KB: 8 waves x [2 rows][256] attn

    const int tid  = threadIdx.x;
    const int lane = tid & 63;
    const int wv   = __builtin_amdgcn_readfirstlane(tid >> 6);  // 0..7, forced uniform

    // XCD-grouped remap: 4 whole batches per XCD -> ekt/V L2-hot
    const int o   = ((blockIdx.x & 7) << 6) + (blockIdx.x >> 3);
    const int b   = o >> 4;
    const int q0  = (o & 15) << 4;
    const int qr0 = q0 + (wv << 1);   // wave's 2 q rows: qr0, qr0+1

    const float*  eqg = eqs + (size_t)(b * 256 + qr0) * 128;       // wave-uniform
    const float4* ekp = (const float4*)(ekt + (size_t)b * 32768);

    // ---- score phase: lane = k (4 tiles of 64); rational-4 over h ----
    float sc[4][2];
    #pragma unroll
    for (int t = 0; t < 4; ++t) {
        float s0 = 0.f, s1 = 0.f;
        #pragma unroll 4
        for (int g = 0; g < 32; ++g) {
            float4 k4 = ekp[((t << 5) + g) * 64 + lane];            // global, L2-hot
            float4 w4 = *(const float4*)(w_g + (g << 2));           // s_load
            float4 e0 = *(const float4*)(eqg + (g << 2));           // s_load
            float4 e1 = *(const float4*)(eqg + 128 + (g << 2));     // s_load
            {
                float d0 = fmaf(e0.x, k4.x, 1.f), d1 = fmaf(e0.y, k4.y, 1.f);
                float d2 = fmaf(e0.z, k4.z, 1.f), d3 = fmaf(e0.w, k4.w, 1.f);
                float P01 = d0 * d1, P23 = d2 * d3;
                float N01 = fmaf(w4.x, d1, w4.y * d0);
                float N23 = fmaf(w4.z, d3, w4.w * d2);
                float num = fmaf(N01, P23, N23 * P01);
                s0 = fmaf(num, __builtin_amdgcn_rcpf(P01 * P23), s0);
            }
            {
                float d0 = fmaf(e1.x, k4.x, 1.f), d1 = fmaf(e1.y, k4.y, 1.f);
                float d2 = fmaf(e1.z, k4.z, 1.f), d3 = fmaf(e1.w, k4.w, 1.f);
                float P01 = d0 * d1, P23 = d2 * d3;
                float N01 = fmaf(w4.x, d1, w4.y * d0);
                float N23 = fmaf(w4.z, d3, w4.w * d2);
                float num = fmaf(N01, P23, N23 * P01);
                s1 = fmaf(num, __builtin_amdgcn_rcpf(P01 * P23), s1);
            }
        }
        sc[t][0] = s0; sc[t][1] = s1;
    }

    // ---- softmax per row, in registers (lane holds k = 64t+lane) ----
    float* strip = sattn + (wv << 9);    // [r*256 + k]
    #pragma unroll
    for (int r = 0; r < 2; ++r) {
        float x0 = -C2 * sc[0][r], x1 = -C2 * sc[1][r];
        float x2 = -C2 * sc[2][r], x3 = -C2 * sc[3][r];
        float m = fmaxf(fmaxf(x0, x1), fmaxf(x2, x3));
        #pragma unroll
        for (int off = 32; off; off >>= 1) m = fmaxf(m, __shfl_xor(m, off));
        float e0 = __builtin_amdgcn_exp2f(x0 - m);
        float e1 = __builtin_amdgcn_exp2f(x1 - m);
        float e2 = __builtin_amdgcn_exp2f(x2 - m);
        float e3 = __builtin_amdgcn_exp2f(x3 - m);
        float sum = (e0 + e1) + (e2 + e3);
        #pragma unroll
        for (int off = 32; off; off >>= 1) sum += __shfl_xor(sum, off);
        float inv = __builtin_amdgcn_rcpf(sum);
        strip[(r << 8) + lane]       = e0 * inv;   // same-wave ds ordering, no barrier
        strip[(r << 8) + 64 + lane]  = e1 * inv;
        strip[(r << 8) + 128 + lane] = e2 * inv;
        strip[(r << 8) + 192 + lane] = e3 * inv;
    }

    // ---- PV: lane = h-pair (h = 2*lane, 2*lane+1); attn via LDS float4 bcast ----
    float2 o0, o1;
    o0.x = o0.y = o1.x = o1.y = 0.f;
    const float2* vp = (const float2*)(v_g + (size_t)b * 32768) + lane;   // + k*64
    #pragma unroll 8
    for (int j4 = 0; j4 < 64; ++j4) {
        float4 a0 = *(const float4*)(strip + (j4 << 2));          // row 0 attn bcast
        float4 a1 = *(const float4*)(strip + 256 + (j4 << 2));    // row 1 attn bcast
        #pragma unroll
        for (int i = 0; i < 4; ++i) {
            float2 v2 = vp[((j4 << 2) + i) << 6];                 // 512B coalesced
            float c0 = (&a0.x)[i], c1 = (&a1.x)[i];
            o0.x = fmaf(c0, v2.x, o0.x); o0.y = fmaf(c0, v2.y, o0.y);
            o1.x = fmaf(c1, v2.x, o1.x); o1.y = fmaf(c1, v2.y, o1.y);
        }
    }

    float* ob = out + (size_t)(b * 256 + qr0) * 128 + (lane << 1);
    *(float2*)(ob)       = o0;
    *(float2*)(ob + 128) = o1;
}

extern "C" void kernel_launch(void* const* d_in, const int* in_sizes, int n_in,
                              void* d_out, int out_size, void* d_ws, size_t ws_size,
                              hipStream_t stream) {
    const float* q = (const float*)d_in[0];
    const float* k = (const float*)d_in[1];
    const float* v = (const float*)d_in[2];
    const float* w = (const float*)d_in[3];
    float* out = (float*)d_out;
    float* ekt = (float*)d_ws;                         // 4 MB
    float* eqs = (float*)d_ws + (32 * 256 * 128);      // 4 MB (ws >= 8 MB)
    addattn_prep<<<1024, 512, 0, stream>>>(k, q, ekt, eqs);
    addattn_kernel<<<512, 512, 0, stream>>>(eqs, ekt, v, w, out);
}